// Round 1
// baseline (515.713 us; speedup 1.0000x reference)
//
#include <hip/hip_runtime.h>
#include <hip/hip_bf16.h>

#define DIM 512
#define BM 64
#define BK 32
#define LSTRIDE 40   // BK + 8 bf16 pad -> 80 B rows, conflict-free b128 frag reads

typedef __bf16 bf16x8 __attribute__((ext_vector_type(8)));
typedef float f32x16 __attribute__((ext_vector_type(16)));

union B128 { uint4 u; bf16x8 v; };

__device__ __forceinline__ unsigned short f2bf(float f) {
    union { __hip_bfloat16 b; unsigned short u; } c;
    c.b = __float2bfloat16(f);
    return c.u;
}

// S[e][d] = bf16(A[e][d] + A[d][e])
__global__ void prep_s_kernel(const float* __restrict__ A,
                              unsigned short* __restrict__ S) {
    int i = blockIdx.x * 256 + threadIdx.x;   // 0 .. 512*512-1
    int e = i >> 9;
    int d = i & 511;
    S[i] = f2bf(A[e * DIM + d] + A[d * DIM + e]);
}

// out[b][0:512] = p[b] + q[b] . S^T   (S symmetric)
// out[b][512:1024] = q[b]             (exact fp32 copy, fused into staging)
__global__ __launch_bounds__(512, 4) void fused_gemm_kernel(
        const float* __restrict__ pq,
        const unsigned short* __restrict__ S,
        float* __restrict__ out) {
    __shared__ __align__(16) unsigned short qs[BM * LSTRIDE];    // 5120 B  (+pad)
    __shared__ __align__(16) unsigned short ss[DIM * LSTRIDE];   // 40960 B (+pad)

    const int t = threadIdx.x;
    const int l = t & 63;
    const int w = t >> 6;        // wave 0..7
    const int wm = w >> 2;       // 0..1  (M position, 32 rows each)
    const int wn = w & 3;        // 0..3  (N position within 128-chunk)
    const int half = l >> 5;     // 0..1
    const int lane31 = l & 31;
    const int m0 = blockIdx.x * BM;

    f32x16 acc[4];
    #pragma unroll
    for (int nt = 0; nt < 4; ++nt)
        #pragma unroll
        for (int r = 0; r < 16; ++r) acc[nt][r] = 0.0f;

    const int qrow = t >> 3;         // 0..63
    const int qcol = (t & 7) * 4;    // 0..28

    for (int kc = 0; kc < DIM / BK; ++kc) {
        const int k0 = kc * BK;

        // ---- stage q tile: global fp32 read, exact copy to out, bf16 to LDS
        const size_t qoff = (size_t)(m0 + qrow) * (2 * DIM) + DIM + k0 + qcol;
        float4 qv = *(const float4*)(pq + qoff);
        *(float4*)(out + qoff) = qv;

        if (kc) __syncthreads();   // previous iter's frag reads done

        ushort4 qb;
        qb.x = f2bf(qv.x); qb.y = f2bf(qv.y); qb.z = f2bf(qv.z); qb.w = f2bf(qv.w);
        *(ushort4*)&qs[qrow * LSTRIDE + qcol] = qb;

        // ---- stage S tile: 512 x 32 bf16, 4 x 16B chunks per thread
        #pragma unroll
        for (int i = 0; i < 4; ++i) {
            int ch = i * 512 + t;          // 0..2047
            int srow = ch >> 2;            // 0..511
            int scol = (ch & 3) * 8;       // 0,8,16,24
            uint4 sv = *(const uint4*)(S + (size_t)srow * DIM + k0 + scol);
            *(uint4*)&ss[srow * LSTRIDE + scol] = sv;
        }
        __syncthreads();

        // ---- MFMA: wave computes 32(M) x {4 x 32}(N), K=32 this chunk
        B128 a0, a1;
        const int arow = 32 * wm + lane31;
        a0.u = *(const uint4*)&qs[arow * LSTRIDE + half * 8];
        a1.u = *(const uint4*)&qs[arow * LSTRIDE + 16 + half * 8];
        #pragma unroll
        for (int nt = 0; nt < 4; ++nt) {
            const int brow = 128 * nt + 32 * wn + lane31;
            B128 b0, b1;
            b0.u = *(const uint4*)&ss[brow * LSTRIDE + half * 8];
            b1.u = *(const uint4*)&ss[brow * LSTRIDE + 16 + half * 8];
            acc[nt] = __builtin_amdgcn_mfma_f32_32x32x16_bf16(a0.v, b0.v, acc[nt], 0, 0, 0);
            acc[nt] = __builtin_amdgcn_mfma_f32_32x32x16_bf16(a1.v, b1.v, acc[nt], 0, 0, 0);
        }
    }

    // ---- epilogue: out[:, :512] = p + pterm
    // C/D layout (verified m74/m101): col = lane&31, row = (r&3) + 8*(r>>2) + 4*(lane>>5)
    #pragma unroll
    for (int nt = 0; nt < 4; ++nt) {
        const int col = 128 * nt + 32 * wn + lane31;
        #pragma unroll
        for (int r = 0; r < 16; ++r) {
            const int row = m0 + 32 * wm + 4 * half + (r & 3) + 8 * (r >> 2);
            const size_t off = (size_t)row * (2 * DIM) + col;
            out[off] = pq[off] + acc[nt][r];
        }
    }
}

extern "C" void kernel_launch(void* const* d_in, const int* in_sizes, int n_in,
                              void* d_out, int out_size, void* d_ws, size_t ws_size,
                              hipStream_t stream) {
    const float* pq = (const float*)d_in[0];
    const float* A  = (const float*)d_in[1];
    float* out = (float*)d_out;
    unsigned short* S = (unsigned short*)d_ws;   // 512*512*2 = 512 KB scratch

    prep_s_kernel<<<(DIM * DIM) / 256, 256, 0, stream>>>(A, S);
    fused_gemm_kernel<<<65536 / BM, 512, 0, stream>>>(pq, S, out);
}